// Round 3
// baseline (120.142 us; speedup 1.0000x reference)
//
#include <hip/hip_runtime.h>
#include <hip/hip_bf16.h>

// VQ-VAE vector quantizer, MI355X — latency-optimized, LDS-free hot path.
// [k_prep]  emb fp32 -> E bf16 + cn = ||e_k||^2
// [k_main]  1024 blocks x 256thr. Block = 32 rows (one b, 32 hw). Each wave owns a
//           disjoint 256-code slice: A-frags direct from lat (strided fp32->bf16),
//           B-frags direct from E (aligned 16B), mfma_16x16x32_bf16, in-wave argmin.
//           No LDS / barriers in main loop. Fused gather q=emb[k*] + loss partial.
// [k_final] vq_loss = 1.25 * sum / (N*D)

typedef __attribute__((ext_vector_type(8))) short bf16x8;
typedef __attribute__((ext_vector_type(4))) float f32x4;

// workspace layout (bytes)
#define WS_E 0u         // bf16 [1024][128] = 262144
#define WS_C 262144u    // f32  [1024]      = 4096
#define WS_P 266240u    // f32  [1024]      = 4096

static __device__ inline short f2bf(float f) {
    __hip_bfloat16 h = __float2bfloat16(f);
    return *reinterpret_cast<short*>(&h);
}

// ---------------- codebook prep: bf16 copy + squared norms ----------------
__global__ __launch_bounds__(128) void k_prep(const float* __restrict__ emb,
                                              __hip_bfloat16* __restrict__ E,
                                              float* __restrict__ cn) {
    int k = blockIdx.x, d = threadIdx.x;
    float v = emb[(k << 7) + d];
    E[(k << 7) + d] = __float2bfloat16(v);
    float s = v * v;
#pragma unroll
    for (int m = 1; m < 64; m <<= 1) s += __shfl_xor(s, m);
    __shared__ float sh[2];
    if ((threadIdx.x & 63) == 0) sh[threadIdx.x >> 6] = s;
    __syncthreads();
    if (threadIdx.x == 0) cn[k] = sh[0] + sh[1];
}

// ---------------- main ----------------
__global__ __launch_bounds__(256, 4) void k_main(const float* __restrict__ lat,
                                                 const float* __restrict__ emb,
                                                 const __hip_bfloat16* __restrict__ E,
                                                 const float* __restrict__ cn,
                                                 float* __restrict__ outq,
                                                 float* __restrict__ partial) {
    __shared__ float cs[128];
    __shared__ int   ci[128];
    __shared__ int   win[32];

    const int t = threadIdx.x, bm = blockIdx.x;
    const int lane = t & 63, wid = t >> 6;
    const int l15 = lane & 15, lg = lane >> 4;
    const int b = bm >> 5, hw0 = (bm & 31) << 5;
    const float* latb = lat + ((size_t)b << 17) + hw0;
    const char* Eb = (const char*)E;

    // ---- A-frags straight from global (all waves same addrs -> L1 dedup) ----
    bf16x8 af[2][4];
    float rn = 0.f;                       // wave 0's lanes jointly cover every value once
#pragma unroll
    for (int m = 0; m < 2; ++m)
#pragma unroll
        for (int ks = 0; ks < 4; ++ks) {
            const float* p = latb + ((size_t)(ks * 32 + lg * 8) << 10) + m * 16 + l15;
            bf16x8 v;
#pragma unroll
            for (int j = 0; j < 8; ++j) {
                float f = p[(size_t)j << 10];
                rn = fmaf(f, f, rn);
                v[j] = f2bf(f);
            }
            af[m][ks] = v;
        }

    // ---- main loop: this wave's codes [wid*256, +256), 8 iters x 32 codes ----
    float run_s[2][4]; int run_i[2][4];
#pragma unroll
    for (int m = 0; m < 2; ++m)
#pragma unroll
        for (int r = 0; r < 4; ++r) { run_s[m][r] = 3.0e38f; run_i[m][r] = 0; }

#pragma unroll
    for (int it = 0; it < 8; ++it) {
        const int kg0 = (wid << 8) + (it << 5);
        bf16x8 bfv[2][4];
#pragma unroll
        for (int c = 0; c < 2; ++c) {
            const char* rowp = Eb + ((size_t)(kg0 + c * 16 + l15) << 8) + lg * 16;
#pragma unroll
            for (int ks = 0; ks < 4; ++ks)
                bfv[c][ks] = *(const bf16x8*)(rowp + ks * 64);
        }
        f32x4 acc[2][2];
#pragma unroll
        for (int m = 0; m < 2; ++m)
#pragma unroll
            for (int c = 0; c < 2; ++c) acc[m][c] = (f32x4){0.f, 0.f, 0.f, 0.f};
#pragma unroll
        for (int ks = 0; ks < 4; ++ks)
#pragma unroll
            for (int m = 0; m < 2; ++m)
#pragma unroll
                for (int c = 0; c < 2; ++c)
                    acc[m][c] = __builtin_amdgcn_mfma_f32_16x16x32_bf16(af[m][ks], bfv[c][ks], acc[m][c], 0, 0, 0);
        // fold (k ascending -> strict < keeps lowest idx)
#pragma unroll
        for (int c = 0; c < 2; ++c) {
            int kg = kg0 + c * 16 + l15;
            float cv = cn[kg];
#pragma unroll
            for (int m = 0; m < 2; ++m)
#pragma unroll
                for (int r = 0; r < 4; ++r) {
                    float s = fmaf(-2.0f, acc[m][c][r], cv);
                    if (s < run_s[m][r]) { run_s[m][r] = s; run_i[m][r] = kg; }
                }
        }
    }

    // ---- in-wave butterfly over the 16 cols, per-wave candidates to LDS ----
#pragma unroll
    for (int m = 0; m < 2; ++m)
#pragma unroll
        for (int r = 0; r < 4; ++r) {
            float s = run_s[m][r]; int bi = run_i[m][r];
#pragma unroll
            for (int mask = 1; mask < 16; mask <<= 1) {
                float os = __shfl_xor(s, mask);
                int   oi = __shfl_xor(bi, mask);
                if (os < s || (os == s && oi < bi)) { s = os; bi = oi; }
            }
            if (l15 == 0) {
                int row = m * 16 + lg * 4 + r;     // C row = (lane>>4)*4 + reg
                cs[(wid << 5) + row] = s;
                ci[(wid << 5) + row] = bi;
            }
        }
    __syncthreads();

    // ---- wave 0: merge 4 waves per row, write win[], block loss partial ----
    if (wid == 0) {
        float bs = 0.f; int bi = 0;
        if (lane < 32) {
            bs = cs[lane]; bi = ci[lane];
#pragma unroll
            for (int w = 1; w < 4; ++w) {
                float s2 = cs[(w << 5) + lane]; int i2 = ci[(w << 5) + lane];
                if (s2 < bs || (s2 == bs && i2 < bi)) { bs = s2; bi = i2; }
            }
            win[lane] = bi;
        }
        float v = (lane < 32 ? bs : 0.f) + rn;     // rn: wave0 lanes cover all x^2 once
#pragma unroll
        for (int m = 1; m < 64; m <<= 1) v += __shfl_xor(v, m);
        if (lane == 0) partial[bm] = v;
    }
    __syncthreads();

    // ---- gather q = emb[k*] fp32, store [B,D,H,W] coalesced ----
    {
        int row = t & 31, dgrp = t >> 5;           // 8 dgrps x 16 d
        int bi = win[row];
        const float4* eg = (const float4*)(emb + ((size_t)bi << 7) + dgrp * 16);
        float* ob = outq + ((size_t)b << 17) + ((size_t)dgrp << 14) + hw0 + row;
#pragma unroll
        for (int jj = 0; jj < 4; ++jj) {
            float4 v = eg[jj];
            ob[(size_t)(jj * 4 + 0) << 10] = v.x;
            ob[(size_t)(jj * 4 + 1) << 10] = v.y;
            ob[(size_t)(jj * 4 + 2) << 10] = v.z;
            ob[(size_t)(jj * 4 + 3) << 10] = v.w;
        }
    }
}

__global__ __launch_bounds__(256) void k_final(const float* __restrict__ partial,
                                               float* __restrict__ loss) {
    float s = partial[threadIdx.x] + partial[threadIdx.x + 256]
            + partial[threadIdx.x + 512] + partial[threadIdx.x + 768];
#pragma unroll
    for (int m = 1; m < 64; m <<= 1) s += __shfl_xor(s, m);
    __shared__ float sh[4];
    if ((threadIdx.x & 63) == 0) sh[threadIdx.x >> 6] = s;
    __syncthreads();
    if (threadIdx.x == 0) loss[0] = (sh[0] + sh[1] + sh[2] + sh[3]) * (1.25f / 4194304.0f);
}

extern "C" void kernel_launch(void* const* d_in, const int* in_sizes, int n_in,
                              void* d_out, int out_size, void* d_ws, size_t ws_size,
                              hipStream_t stream) {
    const float* lat = (const float*)d_in[0];   // [32,128,32,32]
    const float* emb = (const float*)d_in[1];   // [1024,128]
    float* out = (float*)d_out;                 // q (4194304) + vq_loss (1)
    char* ws = (char*)d_ws;
    __hip_bfloat16* E = (__hip_bfloat16*)(ws + WS_E);
    float* cn  = (float*)(ws + WS_C);
    float* prt = (float*)(ws + WS_P);

    k_prep <<<1024, 128, 0, stream>>>(emb, E, cn);
    k_main <<<1024, 256, 0, stream>>>(lat, emb, E, cn, out, prt);
    k_final<<<1,    256, 0, stream>>>(prt, out + 4194304);
}

// Round 4
// 64.360 us; speedup vs baseline: 1.8667x; 1.8667x over previous
//
#include <hip/hip_runtime.h>
#include <hip/hip_bf16.h>

// VQ-VAE vector quantizer, MI355X — partial-argmin GEMM decomposition.
// [k_prep]  emb -> swizzled bf16 E + cn=||e||^2 ; zero loss cell
// [k_trans] lat -> swizzled bf16 A[N][128] (LDS transpose) ; atomicAdd sum(lat^2)
// [k_score] 256 Mtiles x 8 Ntiles: global_load_lds A/E tiles, 1 barrier,
//           mfma_16x16x32_bf16, per-row partial argmin over 128 codes -> ws
// [k_merge] merge 8 partials, gather q=emb[k*] -> [B,D,H,W], atomicAdd sum(s*)

typedef __attribute__((ext_vector_type(8))) short bf16x8;
typedef __attribute__((ext_vector_type(4))) float f32x4;

// workspace layout (bytes)
#define WS_E  0u          // bf16 swz [1024][128]  = 262144
#define WS_C  262144u     // f32 cn [1024]         = 4096
#define WS_A  266240u     // bf16 swz [32768][128] = 8388608
#define WS_PS 8654848u    // f32 part_s [8][32768] = 1048576
#define WS_PI 9703424u    // i32 part_i [8][32768] = 1048576

#define LOSS_SCALE (1.25f / 4194304.0f)

static __device__ inline short f2bf(float f) {
    __hip_bfloat16 h = __float2bfloat16(f);
    return *reinterpret_cast<short*>(&h);
}

static __device__ inline void gload_lds16(const void* g, void* l) {
    __builtin_amdgcn_global_load_lds(
        (const __attribute__((address_space(1))) unsigned int*)g,
        (__attribute__((address_space(3))) unsigned int*)l, 16, 0, 0);
}

// ---------------- codebook prep ----------------
// 64 blocks x 256thr; block = 16 codes. Swizzled E row: chunk c16 at (c16*16)^((row&7)<<4).
__global__ __launch_bounds__(256) void k_prep(const float* __restrict__ emb,
                                              char* __restrict__ Eb,
                                              float* __restrict__ cn,
                                              float* __restrict__ loss) {
    const int t = threadIdx.x;
    const int row = (blockIdx.x << 4) + (t >> 4), c16 = t & 15;
    const float4* ep = (const float4*)(emb + ((size_t)row << 7) + (c16 << 3));
    float4 e0 = ep[0], e1 = ep[1];
    float s = e0.x*e0.x + e0.y*e0.y + e0.z*e0.z + e0.w*e0.w
            + e1.x*e1.x + e1.y*e1.y + e1.z*e1.z + e1.w*e1.w;
#pragma unroll
    for (int m = 1; m < 16; m <<= 1) s += __shfl_xor(s, m);
    if (c16 == 0) cn[row] = s;
    bf16x8 v;
    v[0]=f2bf(e0.x); v[1]=f2bf(e0.y); v[2]=f2bf(e0.z); v[3]=f2bf(e0.w);
    v[4]=f2bf(e1.x); v[5]=f2bf(e1.y); v[6]=f2bf(e1.z); v[7]=f2bf(e1.w);
    *(bf16x8*)(Eb + row * 256 + ((c16 * 16) ^ ((row & 7) << 4))) = v;
    if (blockIdx.x == 0 && t == 0) loss[0] = 0.f;
}

// ---------------- transpose latents -> swizzled bf16 A + sum(lat^2) ----------------
// 1024 blocks x 256thr; block = one b, 32 hw, all 128 d.
__global__ __launch_bounds__(256) void k_trans(const float* __restrict__ lat,
                                               char* __restrict__ Ab,
                                               float* __restrict__ loss) {
    __shared__ float Tf[4096];   // [128 d][32 hw], col-swizzled
    __shared__ float r4[4];
    const int t = threadIdx.x, bm = blockIdx.x;
    const int b = bm >> 5, hw0 = (bm & 31) << 5;
    const float* latp = lat + ((size_t)b << 17) + hw0;

    float rn = 0.f;
#pragma unroll
    for (int i = 0; i < 4; ++i) {
        int idx = i * 256 + t;
        int d = idx >> 3, hw4 = (idx & 7) << 2;
        float4 v = *(const float4*)(latp + ((size_t)d << 10) + hw4);
        rn = fmaf(v.x, v.x, fmaf(v.y, v.y, fmaf(v.z, v.z, fmaf(v.w, v.w, rn))));
        *(float4*)(&Tf[(d << 5) + (hw4 ^ (((d >> 3) & 7) << 2))]) = v;
    }
    __syncthreads();

    const int c16 = t & 15, rowl = t >> 4;
#pragma unroll
    for (int rg = 0; rg < 2; ++rg) {
        int row = rg * 16 + rowl;
        bf16x8 v;
#pragma unroll
        for (int j = 0; j < 8; ++j)
            v[j] = f2bf(Tf[((c16 * 8 + j) << 5) + (row ^ ((c16 & 7) << 2))]);
        *(bf16x8*)(Ab + (size_t)((bm << 5) + row) * 256 + ((c16 * 16) ^ ((row & 7) << 4))) = v;
    }

#pragma unroll
    for (int m = 1; m < 64; m <<= 1) rn += __shfl_xor(rn, m);
    if ((t & 63) == 0) r4[t >> 6] = rn;
    __syncthreads();
    if (t == 0) atomicAdd(loss, (r4[0] + r4[1] + r4[2] + r4[3]) * LOSS_SCALE);
}

// ---------------- partial argmin GEMM ----------------
// 2048 blocks: mt = bid&255 (128 rows), nt = bid>>8 (128 codes). Same-mt -> same XCD.
__global__ __launch_bounds__(256) void k_score(const char* __restrict__ Ab,
                                               const char* __restrict__ Eb,
                                               const float* __restrict__ cn,
                                               float* __restrict__ part_s,
                                               int* __restrict__ part_i) {
    __shared__ char lds[65536];
    char* ldsA = lds;            // 128 rows * 256 B, swizzled
    char* ldsE = lds + 32768;
    const int t = threadIdx.x;
    const int mt = blockIdx.x & 255, nt = blockIdx.x >> 8;
    const int lane = t & 63, wid = t >> 6;
    const int l15 = lane & 15, lg = lane >> 4;
    const int C0 = nt << 7, R0 = mt << 7;

    float cnv[8];
#pragma unroll
    for (int c = 0; c < 8; ++c) cnv[c] = cn[C0 + c * 16 + l15];

    // stage both tiles (32 KB each) via global_load_lds, lane-linear
    {
        const char* Ag = Ab + ((size_t)mt << 15);
        const char* Eg = Eb + ((size_t)nt << 15);
#pragma unroll
        for (int i = 0; i < 8; ++i) {
            int off = (wid << 13) + (i << 10);          // wave-uniform byte base
            gload_lds16(Ag + off + lane * 16, ldsA + off);
            gload_lds16(Eg + off + lane * 16, ldsE + off);
        }
    }
    __syncthreads();

    f32x4 acc[2][8];
#pragma unroll
    for (int m = 0; m < 2; ++m)
#pragma unroll
        for (int c = 0; c < 8; ++c) acc[m][c] = (f32x4){0.f, 0.f, 0.f, 0.f};

#pragma unroll
    for (int ks = 0; ks < 4; ++ks) {
        const int cb = ks * 64 + lg * 16;
        bf16x8 af[2], bf[8];
#pragma unroll
        for (int m = 0; m < 2; ++m) {
            int r = (wid << 5) + m * 16 + l15;
            af[m] = *(const bf16x8*)(ldsA + r * 256 + (cb ^ ((r & 7) << 4)));
        }
#pragma unroll
        for (int c = 0; c < 8; ++c) {
            int r = c * 16 + l15;
            bf[c] = *(const bf16x8*)(ldsE + r * 256 + (cb ^ ((r & 7) << 4)));
        }
#pragma unroll
        for (int m = 0; m < 2; ++m)
#pragma unroll
            for (int c = 0; c < 8; ++c)
                acc[m][c] = __builtin_amdgcn_mfma_f32_16x16x32_bf16(af[m], bf[c], acc[m][c], 0, 0, 0);
    }

    // fold 8 col-tiles into running argmin (k ascending)
    float run_s[2][4]; int run_i[2][4];
#pragma unroll
    for (int m = 0; m < 2; ++m)
#pragma unroll
        for (int r = 0; r < 4; ++r) { run_s[m][r] = 3.0e38f; run_i[m][r] = 0; }
#pragma unroll
    for (int c = 0; c < 8; ++c) {
        int kg = C0 + c * 16 + l15;
        float cv = cnv[c];
#pragma unroll
        for (int m = 0; m < 2; ++m)
#pragma unroll
            for (int r = 0; r < 4; ++r) {
                float s = fmaf(-2.0f, acc[m][c][r], cv);
                if (s < run_s[m][r]) { run_s[m][r] = s; run_i[m][r] = kg; }
            }
    }

    // 16-lane butterfly (cols), then write per-row partials
#pragma unroll
    for (int m = 0; m < 2; ++m)
#pragma unroll
        for (int r = 0; r < 4; ++r) {
            float s = run_s[m][r]; int bi = run_i[m][r];
#pragma unroll
            for (int mask = 1; mask < 16; mask <<= 1) {
                float os = __shfl_xor(s, mask);
                int   oi = __shfl_xor(bi, mask);
                if (os < s || (os == s && oi < bi)) { s = os; bi = oi; }
            }
            run_s[m][r] = s; run_i[m][r] = bi;
        }
    if (l15 == 0) {
#pragma unroll
        for (int m = 0; m < 2; ++m)
#pragma unroll
            for (int r = 0; r < 4; ++r) {
                int row = (wid << 5) + m * 16 + lg * 4 + r;
                part_s[((size_t)nt << 15) + R0 + row] = run_s[m][r];
                part_i[((size_t)nt << 15) + R0 + row] = run_i[m][r];
            }
    }
}

// ---------------- merge partials + gather + loss ----------------
// 512 blocks x 256thr; block = one b, 64 hw rows.
__global__ __launch_bounds__(256) void k_merge(const float* __restrict__ part_s,
                                               const int* __restrict__ part_i,
                                               const float* __restrict__ emb,
                                               float* __restrict__ outq,
                                               float* __restrict__ loss) {
    __shared__ float ms[256];
    __shared__ int   mi[256];
    __shared__ int   win[64];
    const int t = threadIdx.x, bm = blockIdx.x;
    const int b = bm >> 4, hw0 = (bm & 15) << 6;
    const int n0 = (b << 10) + hw0;
    const int w = t >> 6, hwl = t & 63;

    {   // wave w merges nt = 2w, 2w+1
        int n = n0 + hwl;
        float s0 = part_s[((size_t)(2 * w) << 15) + n];
        int   i0 = part_i[((size_t)(2 * w) << 15) + n];
        float s1 = part_s[((size_t)(2 * w + 1) << 15) + n];
        int   i1 = part_i[((size_t)(2 * w + 1) << 15) + n];
        if (s1 < s0 || (s1 == s0 && i1 < i0)) { s0 = s1; i0 = i1; }
        ms[(w << 6) + hwl] = s0; mi[(w << 6) + hwl] = i0;
    }
    __syncthreads();
    if (w == 0) {
        float bs = ms[hwl]; int bi = mi[hwl];
#pragma unroll
        for (int w2 = 1; w2 < 4; ++w2) {
            float s2 = ms[(w2 << 6) + hwl]; int i2 = mi[(w2 << 6) + hwl];
            if (s2 < bs || (s2 == bs && i2 < bi)) { bs = s2; bi = i2; }
        }
        win[hwl] = bi;
        float v = bs;
#pragma unroll
        for (int m = 1; m < 64; m <<= 1) v += __shfl_xor(v, m);
        if (hwl == 0) atomicAdd(loss, v * LOSS_SCALE);
    }
    __syncthreads();

    {   // gather q = emb[k*] fp32, store [B,D,H,W] (64-lane 256B segments)
        const int row = t & 63, dgrp = t >> 6;          // 4 dgrps x 32 d
        const int bi = win[row];
        const float4* eg = (const float4*)(emb + ((size_t)bi << 7) + (dgrp << 5));
        float* ob = outq + ((size_t)b << 17) + ((size_t)(dgrp << 5) << 10) + hw0 + row;
#pragma unroll
        for (int jj = 0; jj < 8; ++jj) {
            float4 v = eg[jj];
            ob[(size_t)(jj * 4 + 0) << 10] = v.x;
            ob[(size_t)(jj * 4 + 1) << 10] = v.y;
            ob[(size_t)(jj * 4 + 2) << 10] = v.z;
            ob[(size_t)(jj * 4 + 3) << 10] = v.w;
        }
    }
}

extern "C" void kernel_launch(void* const* d_in, const int* in_sizes, int n_in,
                              void* d_out, int out_size, void* d_ws, size_t ws_size,
                              hipStream_t stream) {
    const float* lat = (const float*)d_in[0];   // [32,128,32,32]
    const float* emb = (const float*)d_in[1];   // [1024,128]
    float* out = (float*)d_out;                 // q (4194304) + vq_loss (1)
    char* ws = (char*)d_ws;
    char*  E    = ws + WS_E;
    float* cn   = (float*)(ws + WS_C);
    char*  A    = ws + WS_A;
    float* ps   = (float*)(ws + WS_PS);
    int*   pi   = (int*)(ws + WS_PI);
    float* loss = out + 4194304;

    k_prep <<<64,   256, 0, stream>>>(emb, E, cn, loss);
    k_trans<<<1024, 256, 0, stream>>>(lat, A, loss);
    k_score<<<2048, 256, 0, stream>>>(A, E, cn, ps, pi);
    k_merge<<<512,  256, 0, stream>>>(ps, pi, emb, out, loss);
}

// Round 5
// 46.912 us; speedup vs baseline: 2.5610x; 1.3719x over previous
//
#include <hip/hip_runtime.h>
#include <hip/hip_bf16.h>

// VQ-VAE vector quantizer, MI355X — fp8 scores + atomicMin64 merge.
// [memset]  packed[32768] = 0xFF
// [k_stage] 1088 blocks: 1024 trans-blocks: lat -> swz fp8 A[N][128], xsq partials;
//           64 prep-blocks: emb -> swz fp8 E (x512) + cn=||e||^2 fp32; loss=0
// [k_score] 2048 blocks (nt=bid&7, mt=bid>>3): stage A(16K)+E(16K) via global_load_lds,
//           1 barrier, mfma_f32_16x16x32_fp8_fp8, fp32 fold s=cn-(2/512)t,
//           16-lane butterfly, atomicMin64(packed[row], score|idx)
// [k_out]   512 blocks: unpack winners, gather q=emb[k*] fp32 -> [B,D,H,W],
//           loss = 1.25*(sum s* + sum x^2)/(N*D)

typedef __attribute__((ext_vector_type(4))) float f32x4;

// workspace layout (bytes)
#define WS_E   0u          // fp8 swz [1024][128]   = 131072
#define WS_C   131072u     // f32 cn[1024]          = 4096
#define WS_A   135168u     // fp8 swz [32768][128]  = 4194304
#define WS_X   4329472u    // f32 xsq[1024]         = 4096
#define WS_PK  4333568u    // u64 packed[32768]     = 262144

#define LOSS_SCALE (1.25f / 4194304.0f)
#define NEG2_INV_LAMBDA (-2.0f / 512.0f)

static __device__ inline unsigned cvt4_fp8(float a, float b, float c, float d) {
    int v = __builtin_amdgcn_cvt_pk_fp8_f32(a, b, 0, false);
    v = __builtin_amdgcn_cvt_pk_fp8_f32(c, d, v, true);
    return (unsigned)v;
}

static __device__ inline void gload_lds16(const void* g, void* l) {
    __builtin_amdgcn_global_load_lds(
        (const __attribute__((address_space(1))) unsigned int*)g,
        (__attribute__((address_space(3))) unsigned int*)l, 16, 0, 0);
}

// ---------------- stage: trans (bid<1024) | prep (bid>=1024) ----------------
__global__ __launch_bounds__(256) void k_stage(const float* __restrict__ lat,
                                               const float* __restrict__ emb,
                                               char* __restrict__ Ab,
                                               char* __restrict__ Eb,
                                               float* __restrict__ cn,
                                               float* __restrict__ xsq,
                                               float* __restrict__ loss) {
    const int t = threadIdx.x;
    if (blockIdx.x >= 1024) {                       // ---- prep: 16 codes/block ----
        const int pb = blockIdx.x - 1024;
        const int row = (pb << 4) + (t >> 4), c = t & 15;
        const float4* ep = (const float4*)(emb + ((size_t)row << 7) + (c << 3));
        float4 e0 = ep[0], e1 = ep[1];
        float s = e0.x*e0.x + e0.y*e0.y + e0.z*e0.z + e0.w*e0.w
                + e1.x*e1.x + e1.y*e1.y + e1.z*e1.z + e1.w*e1.w;
#pragma unroll
        for (int m = 1; m < 16; m <<= 1) s += __shfl_xor(s, m);
        if (c == 0) cn[row] = s;
        uint2 v;
        v.x = cvt4_fp8(512.f*e0.x, 512.f*e0.y, 512.f*e0.z, 512.f*e0.w);
        v.y = cvt4_fp8(512.f*e1.x, 512.f*e1.y, 512.f*e1.z, 512.f*e1.w);
        *(uint2*)(Eb + row * 128 + ((c * 8) ^ ((row & 7) << 4))) = v;
        if (pb == 0 && t == 0) loss[0] = 0.f;
        return;
    }
    // ---- trans: one b, 32 hw, 128 d ----
    __shared__ float Tf[4096];                      // [128 d][32 hw], col-swizzled
    __shared__ float r4[4];
    const int bm = blockIdx.x;
    const int b = bm >> 5, hw0 = (bm & 31) << 5;
    const float* latp = lat + ((size_t)b << 17) + hw0;

    float rn = 0.f;
#pragma unroll
    for (int i = 0; i < 4; ++i) {
        int idx = i * 256 + t;
        int d = idx >> 3, hw4 = (idx & 7) << 2;
        float4 v = *(const float4*)(latp + ((size_t)d << 10) + hw4);
        rn = fmaf(v.x, v.x, fmaf(v.y, v.y, fmaf(v.z, v.z, fmaf(v.w, v.w, rn))));
        *(float4*)(&Tf[(d << 5) + (hw4 ^ (((d >> 3) & 7) << 2))]) = v;
    }
    __syncthreads();

    {   // column read -> fp8 row (128 B), swizzled 16B chunks
        const int rowl = t & 31, c8 = t >> 5;       // 8 chunk-threads x 32 rows
        float q[16];
#pragma unroll
        for (int j = 0; j < 16; ++j) {
            int d = c8 * 16 + j;
            q[j] = Tf[(d << 5) + (rowl ^ (((d >> 3) & 7) << 2))];
        }
        uint4 w;
        w.x = cvt4_fp8(q[0], q[1], q[2], q[3]);
        w.y = cvt4_fp8(q[4], q[5], q[6], q[7]);
        w.z = cvt4_fp8(q[8], q[9], q[10], q[11]);
        w.w = cvt4_fp8(q[12], q[13], q[14], q[15]);
        *(uint4*)(Ab + (size_t)((bm << 5) + rowl) * 128 +
                  ((c8 * 16) ^ ((rowl & 7) << 4))) = w;
    }

#pragma unroll
    for (int m = 1; m < 64; m <<= 1) rn += __shfl_xor(rn, m);
    if ((t & 63) == 0) r4[t >> 6] = rn;
    __syncthreads();
    if (t == 0) xsq[bm] = r4[0] + r4[1] + r4[2] + r4[3];
}

// ---------------- score: 128 rows x 128 codes, fp8 MFMA, atomicMin merge ----------------
__global__ __launch_bounds__(256, 4) void k_score(const char* __restrict__ Ab,
                                                  const char* __restrict__ Eb,
                                                  const float* __restrict__ cn,
                                                  unsigned long long* __restrict__ packed) {
    __shared__ char lds[32768];
    char* ldsA = lds;                               // 128 rows * 128 B, swizzled
    char* ldsE = lds + 16384;
    const int t = threadIdx.x;
    const int nt = blockIdx.x & 7, mt = blockIdx.x >> 3;   // bid%8 -> XCD pins E-tile
    const int lane = t & 63, wid = t >> 6;
    const int l15 = lane & 15, lg = lane >> 4;
    const int C0 = nt << 7;

    {   // stage A+E tiles (16 KB each), lane-linear copies of pre-swizzled images
        const char* Ag = Ab + ((size_t)mt << 14);
        const char* Eg = Eb + ((size_t)nt << 14);
#pragma unroll
        for (int i = 0; i < 4; ++i) {
            int base = i * 4096 + (wid << 10);
            gload_lds16(Ag + base + lane * 16, ldsA + base);
            gload_lds16(Eg + base + lane * 16, ldsE + base);
        }
    }
    float cnv[8];
#pragma unroll
    for (int c = 0; c < 8; ++c) cnv[c] = cn[C0 + (c << 4) + l15];
    __syncthreads();

    const int swk = (l15 & 7) << 4;
    f32x4 acc[2][8];
#pragma unroll
    for (int m = 0; m < 2; ++m)
#pragma unroll
        for (int c = 0; c < 8; ++c) acc[m][c] = (f32x4){0.f, 0.f, 0.f, 0.f};

#pragma unroll
    for (int ks = 0; ks < 4; ++ks) {
        const int off = (ks * 32 + lg * 8) ^ swk;
        long av[2], bv[8];
#pragma unroll
        for (int m = 0; m < 2; ++m)
            av[m] = *(const long*)(ldsA + ((wid << 5) + m * 16 + l15) * 128 + off);
#pragma unroll
        for (int c = 0; c < 8; ++c)
            bv[c] = *(const long*)(ldsE + ((c << 4) + l15) * 128 + off);
#pragma unroll
        for (int m = 0; m < 2; ++m)
#pragma unroll
            for (int c = 0; c < 8; ++c)
                acc[m][c] = __builtin_amdgcn_mfma_f32_16x16x32_fp8_fp8(av[m], bv[c], acc[m][c], 0, 0, 0);
    }

    // fp32 fold: s = cn - (2/512)*t ; k ascending -> strict < keeps lowest idx
    float run_s[2][4]; int run_i[2][4];
#pragma unroll
    for (int m = 0; m < 2; ++m)
#pragma unroll
        for (int r = 0; r < 4; ++r) { run_s[m][r] = 3.0e38f; run_i[m][r] = 0; }
#pragma unroll
    for (int c = 0; c < 8; ++c) {
        int kg = C0 + (c << 4) + l15;
        float cv = cnv[c];
#pragma unroll
        for (int m = 0; m < 2; ++m)
#pragma unroll
            for (int r = 0; r < 4; ++r) {
                float s = fmaf(NEG2_INV_LAMBDA, acc[m][c][r], cv);
                if (s < run_s[m][r]) { run_s[m][r] = s; run_i[m][r] = kg; }
            }
    }

    // butterfly over the 16 lanes sharing each C-row, then atomicMin64 merge
#pragma unroll
    for (int m = 0; m < 2; ++m)
#pragma unroll
        for (int r = 0; r < 4; ++r) {
            float s = run_s[m][r]; int bi = run_i[m][r];
#pragma unroll
            for (int mask = 1; mask < 16; mask <<= 1) {
                float os = __shfl_xor(s, mask);
                int   oi = __shfl_xor(bi, mask);
                if (os < s || (os == s && oi < bi)) { s = os; bi = oi; }
            }
            if (l15 == 0) {
                int row = (mt << 7) + (wid << 5) + m * 16 + lg * 4 + r;
                unsigned u = __float_as_uint(s);
                unsigned mm = (u & 0x80000000u) ? ~u : (u | 0x80000000u);
                unsigned long long pk = (((unsigned long long)mm) << 32) | (unsigned)bi;
                atomicMin(&packed[row], pk);
            }
        }
}

// ---------------- output: gather + loss ----------------
__global__ __launch_bounds__(256) void k_out(const unsigned long long* __restrict__ packed,
                                             const float* __restrict__ emb,
                                             const float* __restrict__ xsq,
                                             float* __restrict__ outq,
                                             float* __restrict__ loss) {
    __shared__ int win[64];
    const int t = threadIdx.x, bm = blockIdx.x;
    const int b = bm >> 4, hw0 = (bm & 15) << 6;
    const int n0 = bm << 6;

    if (t < 64) {                                   // wave 0: winners + sum(s*)
        unsigned long long p = packed[n0 + t];
        win[t] = (int)(unsigned)(p & 0xFFFFFFFFull);
        unsigned mm = (unsigned)(p >> 32);
        unsigned u = (mm & 0x80000000u) ? (mm ^ 0x80000000u) : ~mm;
        float s = __uint_as_float(u);
#pragma unroll
        for (int m = 1; m < 64; m <<= 1) s += __shfl_xor(s, m);
        if (t == 0) atomicAdd(loss, s * LOSS_SCALE);
    } else if (bm == 0 && t < 128) {                // block 0 wave 1: sum(x^2)
        int l = t - 64;
        float v = 0.f;
        for (int i = l; i < 1024; i += 64) v += xsq[i];
#pragma unroll
        for (int m = 1; m < 64; m <<= 1) v += __shfl_xor(v, m);
        if (l == 0) atomicAdd(loss, v * LOSS_SCALE);
    }
    __syncthreads();

    {   // gather q = emb[k*] fp32, store [B,D,H,W] (64-lane 256B segments)
        const int row = t & 63, dg = t >> 6;        // 4 dgrps x 32 d
        const int bi = win[row];
        const float4* eg = (const float4*)(emb + ((size_t)bi << 7) + (dg << 5));
        float* ob = outq + ((size_t)b << 17) + ((size_t)(dg << 5) << 10) + hw0 + row;
#pragma unroll
        for (int jj = 0; jj < 8; ++jj) {
            float4 v = eg[jj];
            ob[(size_t)(jj * 4 + 0) << 10] = v.x;
            ob[(size_t)(jj * 4 + 1) << 10] = v.y;
            ob[(size_t)(jj * 4 + 2) << 10] = v.z;
            ob[(size_t)(jj * 4 + 3) << 10] = v.w;
        }
    }
}

extern "C" void kernel_launch(void* const* d_in, const int* in_sizes, int n_in,
                              void* d_out, int out_size, void* d_ws, size_t ws_size,
                              hipStream_t stream) {
    const float* lat = (const float*)d_in[0];   // [32,128,32,32]
    const float* emb = (const float*)d_in[1];   // [1024,128]
    float* out = (float*)d_out;                 // q (4194304) + vq_loss (1)
    char* ws = (char*)d_ws;
    char*  E    = ws + WS_E;
    float* cn   = (float*)(ws + WS_C);
    char*  A    = ws + WS_A;
    float* xs   = (float*)(ws + WS_X);
    unsigned long long* pk = (unsigned long long*)(ws + WS_PK);
    float* loss = out + 4194304;

    hipMemsetAsync(ws + WS_PK, 0xFF, 262144, stream);
    k_stage<<<1088, 256, 0, stream>>>(lat, emb, A, E, cn, xs, loss);
    k_score<<<2048, 256, 0, stream>>>(A, E, cn, pk);
    k_out  <<<512,  256, 0, stream>>>(pk, emb, xs, out, loss);
}